// Round 3
// baseline (365.198 us; speedup 1.0000x reference)
//
#include <hip/hip_runtime.h>
#include <cmath>

// Izhikevich neuron step, N=8192.
// I = w@g + x_in (256 MiB fp32 matvec -> memory-bound, HBM floor ~43us),
// then elementwise dynamics; outputs [v_out | spiked_s | u_out | g_out].
//
// R6: falsification round. R5 evidence: izh_kernel absent from top-5
// dispatches (all ~161us 1-GiB harness re-poison fills) => kernel <160us,
// while bench total (349.1us) == old session's total (349.3us) to 0.05%.
// Model: total = ~322us fixed harness fills + ~27-45us kernel at the
// memory floor. This round removes the last two suspected inefficiencies:
//   1. no nontemporal hint on w loads (allow L2/L3 allocation; w is
//      exactly 256 MiB = Infinity Cache size, cross-iter residency
//      possible).
//   2. no LDS staging of g: g is 32 KiB (L1-fit, L2-hot across blocks).
//      Removes the __syncthreads() so w-streaming starts on cycle 0.
// If the total doesn't move, the kernel is at its memory floor and the
// measurement is pinned by harness fills.
//
// Layout: 512-thread blocks (8 waves), one wave per row, 1024 blocks.
// 32 f4 per lane per row, software-pipelined in chunks of 8.

#define NN 8192
#define BLOCK 512
#define ROWS_PER_BLOCK 8      // 8 waves -> 8 rows per block
#define GRID 1024             // NN / ROWS_PER_BLOCK

typedef float f4 __attribute__((ext_vector_type(4)));

__global__ __launch_bounds__(BLOCK) void izh_kernel(
    const float* __restrict__ x_in,
    const float* __restrict__ v,
    const float* __restrict__ u,
    const float* __restrict__ g,
    const float* __restrict__ w,
    const float* __restrict__ a_p,
    const float* __restrict__ b_p,
    const float* __restrict__ c_p,
    const float* __restrict__ d_p,
    float* __restrict__ out)
{
    const int tid  = threadIdx.x;
    const int lane = tid & 63;
    const int wave = tid >> 6;
    const int row  = blockIdx.x * ROWS_PER_BLOCK + wave;

    // Row dot product: 2048 f4 / 64 lanes = 32 f4 per lane.
    // w streamed from HBM (regular loads -> cacheable); g read from
    // global per chunk (32 KiB total: L1/L2-resident, no LDS, no barrier).
    const f4* wrow = (const f4*)(w + (size_t)row * NN);
    const f4* g4   = (const f4*)g;

    float acc0 = 0.0f, acc1 = 0.0f, acc2 = 0.0f, acc3 = 0.0f;

    f4 wv[8];
    #pragma unroll
    for (int k = 0; k < 8; ++k) {
        wv[k] = wrow[lane + 64 * k];
    }

    #pragma unroll
    for (int c = 0; c < 4; ++c) {
        f4 wn[8];
        if (c < 3) {
            #pragma unroll
            for (int k = 0; k < 8; ++k) {
                wn[k] = wrow[(c + 1) * 512 + lane + 64 * k];
            }
        }
        #pragma unroll
        for (int k = 0; k < 8; ++k) {
            const f4 gv = g4[c * 512 + lane + 64 * k];
            acc0 = fmaf(wv[k].x, gv.x, acc0);
            acc1 = fmaf(wv[k].y, gv.y, acc1);
            acc2 = fmaf(wv[k].z, gv.z, acc2);
            acc3 = fmaf(wv[k].w, gv.w, acc3);
        }
        if (c < 3) {
            #pragma unroll
            for (int k = 0; k < 8; ++k) wv[k] = wn[k];
        }
    }
    float acc = (acc0 + acc1) + (acc2 + acc3);

    // Wave-local reduction over 64 lanes; no LDS, no barrier.
    #pragma unroll
    for (int off = 32; off > 0; off >>= 1) {
        acc += __shfl_down(acc, off, 64);
    }

    if (lane == 0) {
        const float dot = acc;

        const float I  = dot + x_in[row];
        const float vv = v[row];
        const float uu = u[row];
        const float gg = g[row];

        const float v1 = vv + (0.04f * vv * vv + 5.0f * vv + 140.0f - uu + I);

        // differentiable spike surrogate
        const float s = 1.0f / (1.0f + expf(-4.0f * (v1 - 30.0f)));

        const float spiked = (v1 >= 30.0f) ? 1.0f : 0.0f;
        const float ns     = 1.0f - spiked;

        const float du = fabsf(a_p[row]) * (fabsf(b_p[row]) * v1 - uu);
        const float dg = -gg / 6.5f;

        out[0 * NN + row] = ns * v1 + spiked * c_p[row];        // v_out
        out[1 * NN + row] = s;                                  // spiked_s
        out[2 * NN + row] = ns * (uu + du) + spiked * d_p[row]; // u_out
        out[3 * NN + row] = ns * (gg + dg) + spiked;            // g_out
    }
}

extern "C" void kernel_launch(void* const* d_in, const int* in_sizes, int n_in,
                              void* d_out, int out_size, void* d_ws, size_t ws_size,
                              hipStream_t stream) {
    // setup_inputs() order: x_in, v, u, g, w, a_p, b_p, c_p, d_p
    const float* x_in = (const float*)d_in[0];
    const float* v    = (const float*)d_in[1];
    const float* u    = (const float*)d_in[2];
    const float* g    = (const float*)d_in[3];
    const float* w    = (const float*)d_in[4];
    const float* a_p  = (const float*)d_in[5];
    const float* b_p  = (const float*)d_in[6];
    const float* c_p  = (const float*)d_in[7];
    const float* d_p  = (const float*)d_in[8];
    float* out = (float*)d_out;

    izh_kernel<<<GRID, BLOCK, 0, stream>>>(x_in, v, u, g, w, a_p, b_p, c_p, d_p, out);
}

// Round 4
// 348.536 us; speedup vs baseline: 1.0478x; 1.0478x over previous
//
#include <hip/hip_runtime.h>
#include <cmath>

// Izhikevich neuron step, N=8192.
// I = w@g + x_in (256 MiB fp32 matvec -> memory-bound, HBM pure-read
// floor ~33us), then elementwise dynamics;
// outputs [v_out | spiked_s | u_out | g_out].
//
// R7 = revert to R5. Evidence chain:
//  - R5 (this structure): total 349.1us. R6 (no nt-loads, no LDS-g):
//    total 365.2us (+16us). Harness re-poison fills are a fixed ~320us
//    (2 x ~160us, 1.07GB each at 83-85% HBM peak) in every profile.
//  - Kernel-attributable part of R5 ~= 29us ~= 268MB / ~8TB/s pure-read
//    HBM peak -> at the memory roofline.
//  - R6's regression isolates: g must stay in LDS (global g loads
//    serialize FMA chunks on the vmcnt queue), and w loads should be
//    nontemporal (256MiB single-use stream; don't churn L2/L3).
//
// Layout: 512-thread blocks (8 waves), ONE WAVE PER ROW, 1024 blocks.
//   - g (32 KiB) staged to LDS once per block, single __syncthreads().
//   - 32 float4 nt-loads per lane per row, software-pipelined in chunks
//     of 8 (explicit prefetch double-buffer).
//   - wave-local __shfl_down reduction, elementwise tail on lane 0.

#define NN 8192
#define BLOCK 512
#define ROWS_PER_BLOCK 8      // 8 waves -> 8 rows per block
#define GRID 1024             // NN / ROWS_PER_BLOCK

typedef float f4 __attribute__((ext_vector_type(4)));

__global__ __launch_bounds__(BLOCK) void izh_kernel(
    const float* __restrict__ x_in,
    const float* __restrict__ v,
    const float* __restrict__ u,
    const float* __restrict__ g,
    const float* __restrict__ w,
    const float* __restrict__ a_p,
    const float* __restrict__ b_p,
    const float* __restrict__ c_p,
    const float* __restrict__ d_p,
    float* __restrict__ out)
{
    __shared__ f4 g_lds[NN / 4];   // 32 KiB

    const int tid  = threadIdx.x;
    const int lane = tid & 63;
    const int wave = tid >> 6;
    const int row  = blockIdx.x * ROWS_PER_BLOCK + wave;

    // Stage g into LDS once per block: 2048 f4 / 512 threads = 4 each,
    // coalesced. (g is hot in L2 after the first few blocks.)
    const f4* g4 = (const f4*)g;
    #pragma unroll
    for (int i = 0; i < (NN / 4) / BLOCK; ++i) {
        g_lds[tid + i * BLOCK] = g4[tid + i * BLOCK];
    }
    __syncthreads();

    // Row dot product: 2048 f4 / 64 lanes = 32 f4 per lane.
    // Chunked 4 x 8 with explicit prefetch double-buffer: 8-16 global
    // loads in flight at all times, LDS reads overlap on the lgkm pipe.
    const f4* wrow = (const f4*)(w + (size_t)row * NN);

    float acc0 = 0.0f, acc1 = 0.0f, acc2 = 0.0f, acc3 = 0.0f;

    f4 wv[8];
    #pragma unroll
    for (int k = 0; k < 8; ++k) {
        wv[k] = __builtin_nontemporal_load(&wrow[lane + 64 * k]);
    }

    #pragma unroll
    for (int c = 0; c < 4; ++c) {
        f4 wn[8];
        if (c < 3) {
            #pragma unroll
            for (int k = 0; k < 8; ++k) {
                wn[k] = __builtin_nontemporal_load(
                            &wrow[(c + 1) * 512 + lane + 64 * k]);
            }
        }
        #pragma unroll
        for (int k = 0; k < 8; ++k) {
            const f4 gv = g_lds[c * 512 + lane + 64 * k];
            acc0 = fmaf(wv[k].x, gv.x, acc0);
            acc1 = fmaf(wv[k].y, gv.y, acc1);
            acc2 = fmaf(wv[k].z, gv.z, acc2);
            acc3 = fmaf(wv[k].w, gv.w, acc3);
        }
        if (c < 3) {
            #pragma unroll
            for (int k = 0; k < 8; ++k) wv[k] = wn[k];
        }
    }
    float acc = (acc0 + acc1) + (acc2 + acc3);

    // Wave-local reduction over 64 lanes; no LDS, no barrier.
    #pragma unroll
    for (int off = 32; off > 0; off >>= 1) {
        acc += __shfl_down(acc, off, 64);
    }

    if (lane == 0) {
        const float dot = acc;

        const float I  = dot + x_in[row];
        const float vv = v[row];
        const float uu = u[row];
        const float gg = g[row];

        const float v1 = vv + (0.04f * vv * vv + 5.0f * vv + 140.0f - uu + I);

        // differentiable spike surrogate
        const float s = 1.0f / (1.0f + expf(-4.0f * (v1 - 30.0f)));

        const float spiked = (v1 >= 30.0f) ? 1.0f : 0.0f;
        const float ns     = 1.0f - spiked;

        const float du = fabsf(a_p[row]) * (fabsf(b_p[row]) * v1 - uu);
        const float dg = -gg / 6.5f;

        out[0 * NN + row] = ns * v1 + spiked * c_p[row];        // v_out
        out[1 * NN + row] = s;                                  // spiked_s
        out[2 * NN + row] = ns * (uu + du) + spiked * d_p[row]; // u_out
        out[3 * NN + row] = ns * (gg + dg) + spiked;            // g_out
    }
}

extern "C" void kernel_launch(void* const* d_in, const int* in_sizes, int n_in,
                              void* d_out, int out_size, void* d_ws, size_t ws_size,
                              hipStream_t stream) {
    // setup_inputs() order: x_in, v, u, g, w, a_p, b_p, c_p, d_p
    const float* x_in = (const float*)d_in[0];
    const float* v    = (const float*)d_in[1];
    const float* u    = (const float*)d_in[2];
    const float* g    = (const float*)d_in[3];
    const float* w    = (const float*)d_in[4];
    const float* a_p  = (const float*)d_in[5];
    const float* b_p  = (const float*)d_in[6];
    const float* c_p  = (const float*)d_in[7];
    const float* d_p  = (const float*)d_in[8];
    float* out = (float*)d_out;

    izh_kernel<<<GRID, BLOCK, 0, stream>>>(x_in, v, u, g, w, a_p, b_p, c_p, d_p, out);
}